// Round 18
// baseline (372.985 us; speedup 1.0000x reference)
//
#include <hip/hip_runtime.h>
#include <stdint.h>

// CausalSelfAttention: B=128 T=256 C=384 H=6 hd=64
// cvt(f32->bf16) -> GEMM1 qkv(+bias; q,k rows + V TRANSPOSED to vt) ->
// fused causal attention -> GEMM2 proj(+bias, f32)
// All matmuls via v_mfma_f32_16x16x32_bf16. Tolerance is bf16-floor (9.3e-2).

typedef unsigned short u16;
typedef __attribute__((ext_vector_type(8))) short short8;   // 8 bf16 (A/B frag)
typedef __attribute__((ext_vector_type(4))) short short4v;  // 4 bf16 (half frag)
typedef __attribute__((ext_vector_type(4))) float float4v;  // C/D frag

__device__ __forceinline__ u16 f2b(float f){            // f32 -> bf16 RNE
  union { float f; uint32_t u; } cv; cv.f = f;
  uint32_t u = cv.u;
  u += 0x7FFFu + ((u >> 16) & 1u);
  return (u16)(u >> 16);
}

__device__ __forceinline__ u16 f2b_t(float f){          // f32 -> bf16 truncate (1 op)
  union { float f; uint32_t u; } cv; cv.f = f;
  return (u16)(cv.u >> 16);
}

__device__ __forceinline__ float4v mfma16(short8 a, short8 b, float4v c){
  return __builtin_amdgcn_mfma_f32_16x16x32_bf16(a, b, c, 0, 0, 0);
}

// async global->LDS, 16B per lane. LDS dest = wave-uniform base + lane*16.
__device__ __forceinline__ void gld16(const void* g, void* l){
  __builtin_amdgcn_global_load_lds((__attribute__((address_space(1))) const void*)g,
                                   (__attribute__((address_space(3))) void*)l, 16, 0, 0);
}

// ---------------------------------------------------------------------------
// Kernel 1: f32 -> bf16 conversion for x, w_attn, w_proj
// ---------------------------------------------------------------------------
__global__ __launch_bounds__(256) void cvt3(
    const float* __restrict__ a, u16* __restrict__ da, int na,
    const float* __restrict__ b, u16* __restrict__ db, int nb,
    const float* __restrict__ c, u16* __restrict__ dc, int nc)
{
  const int total = na + nb + nc;  // counts in float4 units
  for (int i = blockIdx.x * blockDim.x + threadIdx.x; i < total;
       i += gridDim.x * blockDim.x){
    const float* s; u16* d; int j = i;
    if (j < na)           { s = a; d = da; }
    else if (j < na + nb) { j -= na; s = b; d = db; }
    else                  { j -= na + nb; s = c; d = dc; }
    const float4 v = ((const float4*)s)[j];
    ushort4 o;
    o.x = f2b(v.x); o.y = f2b(v.y); o.z = f2b(v.z); o.w = f2b(v.w);
    ((ushort4*)d)[j] = o;
  }
}

// ---------------------------------------------------------------------------
// Kernel 2: GEMM1 qkv = x(bf16) @ w_attn^T + bias. R16 schedule with
// TWO-buffer LDS (3rd buffer was provably dead: stage(t+2) is issued after
// B2(t) and waited at B1(t+2) -- buf never written while readable):
// 48KB LDS -> 3 blocks/CU = 24 waves/CU = 6 waves/SIMD (was 4).
//   tile t: vmcnt(3)->B1 ; frag ds_reads ; lgkm(0)->B2 ; STAGE(t+2,buf t&1) ; MFMA
// 512 thr / 8 waves, wave tile 64x64, acc[4][4], VGPR 64.
// Epilogue: tn>=768 is V -> written TRANSPOSED to vt[b][h][d][t].
// Grid: 1-D XCD-chunked, yt-fastest.
// ---------------------------------------------------------------------------
__global__ __launch_bounds__(512, 6) void gemm_qkv(
    const u16* __restrict__ A, const u16* __restrict__ B,
    const float* __restrict__ bias, u16* __restrict__ QK,
    u16* __restrict__ Vt)
{
  constexpr int K    = 384;
  constexpr int NKT  = 12;
  constexpr int AB   = 256 * 32;               // 8192 u16 = 16KB per A buffer
  constexpr int BOFF = 2 * AB;
  __shared__ __align__(16) u16 SH[2 * AB + 2 * 4096];   // 48KB

  const int tid  = threadIdx.x;
  const int lane = tid & 63;
  const int wave = tid >> 6;
  const int lrow = lane & 15;
  const int g    = lane >> 4;

  // XCD-chunked decode, yt-fastest: 128 M-tiles (16/XCD) x 9 N-tiles
  const int id    = blockIdx.x;
  const int local = id >> 3;
  const int xtl   = local / 9;
  const int yt    = local - xtl * 9;
  const int tm    = ((id & 7) * 16 + xtl) << 8;
  const int tn    = yt << 7;
  const int wm    = (wave >> 1) * 64;          // 4 wave-rows
  const int wn    = (wave & 1) * 64;           // 2 wave-cols

  float4v acc[4][4];
  #pragma unroll
  for (int i = 0; i < 4; ++i)
    #pragma unroll
    for (int j = 0; j < 4; ++j) acc[i][j] = (float4v){0.f, 0.f, 0.f, 0.f};

  // staging: chunk c (1KB) = 16 rows x 32 cols; LDS granule q of row r holds
  // source granule q ^ ((r>>1)&3)  (R3/R6-verified conflict-free pattern)
  const int srow = lane >> 2;
  const int sg   = ((lane & 3) ^ ((lane >> 3) & 3)) << 3;
  const int key  = (lrow >> 1) & 3;

  auto STAGE = [&](int kt, int buf){           // 3 gld16 / thread
    #pragma unroll
    for (int j = 0; j < 2; ++j){               // A: 16 chunks, 2/wave
      const int c = wave * 2 + j;
      const int row = c * 16 + srow;
      gld16(A + (size_t)(tm + row) * K + kt * 32 + sg, &SH[buf * AB + c * 512]);
    }
    {                                          // B: 8 chunks, 1/wave
      const int c = wave;
      const int row = c * 16 + srow;
      gld16(B + (size_t)(tn + row) * K + kt * 32 + sg, &SH[BOFF + buf * 4096 + c * 512]);
    }
  };

  STAGE(0, 0);
  STAGE(1, 1);
  for (int kt = 0; kt < NKT; ++kt){
    const int b0 = kt & 1;
    if (kt + 1 < NKT) asm volatile("s_waitcnt vmcnt(3)" ::: "memory");
    else              asm volatile("s_waitcnt vmcnt(0)" ::: "memory");
    __builtin_amdgcn_s_barrier();

    const u16* Ac = &SH[b0 * AB];
    const u16* Bc = &SH[BOFF + b0 * 4096];
    short8 af[4], bf[4];
    #pragma unroll
    for (int i = 0; i < 4; ++i)
      af[i] = *(const short8*)&Ac[(wm + i * 16 + lrow) * 32 + ((g ^ key) << 3)];
    #pragma unroll
    for (int ni = 0; ni < 4; ++ni)
      bf[ni] = *(const short8*)&Bc[(wn + ni * 16 + lrow) * 32 + ((g ^ key) << 3)];

    asm volatile("s_waitcnt lgkmcnt(0)" ::: "memory");
    __builtin_amdgcn_sched_barrier(0);
    __builtin_amdgcn_s_barrier();              // B2: all frag reads complete

    if (kt + 2 < NKT) STAGE(kt + 2, b0);       // overwrite just-read buffer

    __builtin_amdgcn_s_setprio(1);
    #pragma unroll
    for (int ni = 0; ni < 4; ++ni)
      #pragma unroll
      for (int mi = 0; mi < 4; ++mi)
        acc[mi][ni] = mfma16(af[mi], bf[ni], acc[mi][ni]);
    __builtin_amdgcn_s_setprio(0);
  }

  // ---- epilogue. D layout: col=lane&15, row=(lane>>4)*4+reg (HW-verified).
  if (tn >= 768){
    // V third -> vt[b][h][d][t]; tm tile (256 rows) == one batch element
    const int bb = tm >> 8;
    #pragma unroll
    for (int ni = 0; ni < 4; ++ni){
      const int vcol0 = tn + wn - 768 + ni * 16;
      const int hh = vcol0 >> 6;
      const int dd = (vcol0 & 63) + lrow;
      const float bs = bias[tn + wn + ni * 16 + lrow];
      u16* vbase = Vt + ((size_t)(bb * 6 + hh) * 64 + dd) * 256;
      #pragma unroll
      for (int mi = 0; mi < 4; ++mi){
        #pragma unroll
        for (int r = 0; r < 4; ++r){
          const int t = wm + mi * 16 + g * 4 + r;
          vbase[t] = f2b(acc[mi][ni][r] + bs);
        }
      }
    }
  } else {
    #pragma unroll
    for (int mi = 0; mi < 4; ++mi){
      #pragma unroll
      for (int ni = 0; ni < 4; ++ni){
        const int gcol = tn + wn + ni * 16 + lrow;
        const float bs = bias[gcol];
        #pragma unroll
        for (int r = 0; r < 4; ++r){
          const int grow = tm + wm + mi * 16 + g * 4 + r;
          QK[(size_t)grow * 768 + gcol] = f2b(acc[mi][ni][r] + bs);
        }
      }
    }
  }
}

// ---------------------------------------------------------------------------
// Kernel 4: GEMM2  out = y @ w_proj^T + bias (f32 out). Two-buffer pipeline,
// BM=128, 8 waves (wave tile 32x64, acc[2][4]): LDS 32KB -> 4 blocks/CU
// (wave cap) = 32 waves/CU = 8/SIMD. 768 blocks at 4/CU -> zero tail.
//   tile t: vmcnt(2)->B1 ; frag ds_reads ; lgkm(0)->B2 ; STAGE(t+2) ; MFMA
// ---------------------------------------------------------------------------
__global__ __launch_bounds__(512, 8) void gemm_proj(
    const u16* __restrict__ A, const u16* __restrict__ B,
    const float* __restrict__ bias, float* __restrict__ Cout)
{
  constexpr int K    = 384;
  constexpr int NKT  = 12;
  constexpr int AB   = 128 * 32;               // 4096 u16 = 8KB per A buffer
  constexpr int BOFF = 2 * AB;
  __shared__ __align__(16) u16 SH[2 * AB + 2 * 4096];   // 32KB

  const int tid  = threadIdx.x;
  const int lane = tid & 63;
  const int wave = tid >> 6;
  const int lrow = lane & 15;
  const int g    = lane >> 4;

  // XCD-chunked, yt-fastest: 256 M-tiles (32/XCD) x 3 N-tiles
  const int id    = blockIdx.x;
  const int local = id >> 3;
  const int xtl   = local / 3;
  const int yt    = local - xtl * 3;
  const int tm    = ((id & 7) * 32 + xtl) << 7;
  const int tn    = yt << 7;
  const int wm    = (wave >> 1) * 32;          // 4 wave-rows of 32
  const int wn    = (wave & 1) * 64;           // 2 wave-cols of 64

  float4v acc[2][4];
  #pragma unroll
  for (int i = 0; i < 2; ++i)
    #pragma unroll
    for (int j = 0; j < 4; ++j) acc[i][j] = (float4v){0.f, 0.f, 0.f, 0.f};

  const int srow = lane >> 2;
  const int sg   = ((lane & 3) ^ ((lane >> 3) & 3)) << 3;
  const int key  = (lrow >> 1) & 3;

  auto STAGE = [&](int kt, int buf){           // 2 gld16 / thread
    {                                          // A: 8 chunks, 1/wave
      const int row = wave * 16 + srow;
      gld16(A + (size_t)(tm + row) * K + kt * 32 + sg, &SH[buf * AB + wave * 512]);
    }
    {                                          // B: 8 chunks, 1/wave
      const int row = wave * 16 + srow;
      gld16(B + (size_t)(tn + row) * K + kt * 32 + sg, &SH[BOFF + buf * 4096 + wave * 512]);
    }
  };

  STAGE(0, 0);
  STAGE(1, 1);
  for (int kt = 0; kt < NKT; ++kt){
    const int b0 = kt & 1;
    if (kt + 1 < NKT) asm volatile("s_waitcnt vmcnt(2)" ::: "memory");
    else              asm volatile("s_waitcnt vmcnt(0)" ::: "memory");
    __builtin_amdgcn_s_barrier();

    const u16* Ac = &SH[b0 * AB];
    const u16* Bc = &SH[BOFF + b0 * 4096];
    short8 af[2], bf[4];
    #pragma unroll
    for (int i = 0; i < 2; ++i)
      af[i] = *(const short8*)&Ac[(wm + i * 16 + lrow) * 32 + ((g ^ key) << 3)];
    #pragma unroll
    for (int ni = 0; ni < 4; ++ni)
      bf[ni] = *(const short8*)&Bc[(wn + ni * 16 + lrow) * 32 + ((g ^ key) << 3)];

    asm volatile("s_waitcnt lgkmcnt(0)" ::: "memory");
    __builtin_amdgcn_sched_barrier(0);
    __builtin_amdgcn_s_barrier();

    if (kt + 2 < NKT) STAGE(kt + 2, b0);

    __builtin_amdgcn_s_setprio(1);
    #pragma unroll
    for (int ni = 0; ni < 4; ++ni)
      #pragma unroll
      for (int mi = 0; mi < 2; ++mi)
        acc[mi][ni] = mfma16(af[mi], bf[ni], acc[mi][ni]);
    __builtin_amdgcn_s_setprio(0);
  }

  #pragma unroll
  for (int mi = 0; mi < 2; ++mi)
    #pragma unroll
    for (int ni = 0; ni < 4; ++ni){
      const int gcol = tn + wn + ni * 16 + lrow;
      const float bs = bias[gcol];
      #pragma unroll
      for (int r = 0; r < 4; ++r){
        const int grow = tm + wm + mi * 16 + g * 4 + r;
        Cout[(size_t)grow * 384 + gcol] = acc[mi][ni][r] + bs;
      }
    }
}

// ---------------------------------------------------------------------------
// Kernel 3: fused causal attention (R17-measured), EIGHT waves (512 thr),
// one workgroup per (b,h), 64KB LDS -> 2 blocks/CU = 4 waves/SIMD.
// Each wave does 2 q-tiles {w, 15-w} = exactly 17 causal tiles (balanced).
// Swapped QK^T; softmax lane-local(+2 shfl); deferred normalization with
// shfl-transported rs; truncating P-convert; V^T pre-transposed from GEMM1.
// ---------------------------------------------------------------------------
__global__ __launch_bounds__(512, 4) void attn_k(
    const u16* __restrict__ qkv, const u16* __restrict__ vt,
    u16* __restrict__ y)
{
  __shared__ u16 Klds[256 * 64];   // K rows (128B), 16B granules XOR'd by row&7
  __shared__ u16 Vlds[64 * 256];   // V^T rows d (512B): unit u at u^(d&7)
  const int tid  = threadIdx.x;
  const int lane = tid & 63;
  const int wave = tid >> 6;       // 0..7
  const int lrow = lane & 15;
  const int g    = lane >> 4;
  const int bh = blockIdx.x;
  const int b = bh / 6, h = bh % 6;
  const u16* qb  = qkv + (size_t)b * 256 * 768 + h * 64;
  const u16* kb  = qb + 384;
  const u16* vtb = vt + (size_t)(b * 6 + h) * 64 * 256;

  // ---- stage K: 32 chunks, 4/wave
  #pragma unroll
  for (int j = 0; j < 4; ++j){
    const int c = wave * 4 + j;
    const int row = c * 8 + (lane >> 3);
    const int col = (((lane & 7) ^ (lane >> 3)) << 3);
    gld16(kb + (size_t)row * 768 + col, &Klds[c * 512]);
  }
  // ---- stage V^T: 32 chunks, 4/wave
  #pragma unroll
  for (int j = 0; j < 4; ++j){
    const int c  = wave * 4 + j;
    const int dd = c * 2 + (lane >> 5);
    const int q  = lane & 31;
    gld16(vtb + (size_t)dd * 256 + ((q ^ (dd & 7)) << 3), &Vlds[c * 512]);
  }
  __syncthreads();

  #pragma unroll
  for (int it = 0; it < 2; ++it){
    const int rb = (it == 0) ? wave : 15 - wave;   // pair = 17 tiles/wave
    const int q0 = rb * 16;
    const u16* qrow = qb + (size_t)(q0 + lrow) * 768 + g * 8;
    const short8 qf0 = *(const short8*)(qrow);
    const short8 qf1 = *(const short8*)(qrow + 32);

    float4v s[16];
    #pragma unroll
    for (int nt = 0; nt < 16; ++nt){
      if (nt <= rb){
        const int row = nt * 16 + lrow;
        const int swk = lrow & 7;
        const short8 k0 = *(const short8*)&Klds[row * 64 + ((g ^ swk) << 3)];
        const short8 k1 = *(const short8*)&Klds[row * 64 + (((4 + g) ^ swk) << 3)];
        float4v a = (float4v){0.f, 0.f, 0.f, 0.f};
        a = mfma16(k0, qf0, a);
        a = mfma16(k1, qf1, a);
        if (nt == rb){
          #pragma unroll
          for (int r = 0; r < 4; ++r)
            a[r] = (g * 4 + r > lrow) ? -1e30f : a[r];
        }
        s[nt] = a;
      }
    }

    float mx = -1e30f;
    #pragma unroll
    for (int nt = 0; nt < 16; ++nt) if (nt <= rb){
      #pragma unroll
      for (int r = 0; r < 4; ++r) mx = fmaxf(mx, s[nt][r]);
    }
    mx = fmaxf(mx, __shfl_xor(mx, 16));
    mx = fmaxf(mx, __shfl_xor(mx, 32));
    float sum = 0.f;
    #pragma unroll
    for (int nt = 0; nt < 16; ++nt) if (nt <= rb){
      #pragma unroll
      for (int r = 0; r < 4; ++r){
        const float p = exp2f((s[nt][r] - mx) * 0.18033688011112042f);
        s[nt][r] = p;
        sum += p;
      }
    }
    sum += __shfl_xor(sum, 16);
    sum += __shfl_xor(sum, 32);
    const float rs = 1.f / sum;            // rs for q = q0 + lrow
    float rsq[4];
    #pragma unroll
    for (int r = 0; r < 4; ++r) rsq[r] = __shfl(rs, g * 4 + r);

    float4v o0 = (float4v){0,0,0,0}, o1 = (float4v){0,0,0,0};
    float4v o2 = (float4v){0,0,0,0}, o3 = (float4v){0,0,0,0};
    const int swk = lrow & 7;
    #pragma unroll
    for (int kt = 0; kt < 8; ++kt){
      if (2 * kt <= rb){
        short8 pa;
        #pragma unroll
        for (int r = 0; r < 4; ++r) pa[r] = (short)f2b_t(s[2 * kt][r]);
        if (2 * kt + 1 <= rb){
          #pragma unroll
          for (int r = 0; r < 4; ++r) pa[4 + r] = (short)f2b_t(s[2 * kt + 1][r]);
        } else {
          #pragma unroll
          for (int r = 0; r < 4; ++r) pa[4 + r] = 0;
        }
        const int plo_e = (((kt * 4 +     (g >> 1)) ^ swk) << 3) + ((g & 1) << 2);
        const int phi_e = (((kt * 4 + 2 + (g >> 1)) ^ swk) << 3) + ((g & 1) << 2);
        #pragma unroll
        for (int dt = 0; dt < 4; ++dt){
          const u16* vrow = &Vlds[(size_t)(dt * 16 + lrow) * 256];
          const short4v vlo = *(const short4v*)&vrow[plo_e];
          const short4v vhi = *(const short4v*)&vrow[phi_e];
          const short8 bf = __builtin_shufflevector(vlo, vhi, 0,1,2,3,4,5,6,7);
          if      (dt == 0) o0 = mfma16(pa, bf, o0);
          else if (dt == 1) o1 = mfma16(pa, bf, o1);
          else if (dt == 2) o2 = mfma16(pa, bf, o2);
          else              o3 = mfma16(pa, bf, o3);
        }
      }
    }

    u16* yb = y + (size_t)(b * 256 + q0) * 384 + h * 64;
    #pragma unroll
    for (int r = 0; r < 4; ++r){
      const int q = g * 4 + r;
      yb[(size_t)q * 384 +  0 + lrow] = f2b(o0[r] * rsq[r]);
      yb[(size_t)q * 384 + 16 + lrow] = f2b(o1[r] * rsq[r]);
      yb[(size_t)q * 384 + 32 + lrow] = f2b(o2[r] * rsq[r]);
      yb[(size_t)q * 384 + 48 + lrow] = f2b(o3[r] * rsq[r]);
    }
  }
}

// ---------------------------------------------------------------------------
extern "C" void kernel_launch(void* const* d_in, const int* in_sizes, int n_in,
                              void* d_out, int out_size, void* d_ws, size_t ws_size,
                              hipStream_t stream)
{
  const float* x      = (const float*)d_in[0];
  const float* w_attn = (const float*)d_in[1];
  const float* b_attn = (const float*)d_in[2];
  const float* w_proj = (const float*)d_in[3];
  const float* b_proj = (const float*)d_in[4];
  float* out = (float*)d_out;

  // workspace layout (bytes)
  char* ws = (char*)d_ws;
  u16* xb  = (u16*)(ws);                 // 25,165,824  x bf16 [32768,384]
  u16* wab = (u16*)(ws + 25165824);      //    884,736  w_attn bf16 [1152,384]
  u16* wpb = (u16*)(ws + 26050560);      //    294,912  w_proj bf16 [384,384]
  u16* qkv = (u16*)(ws + 26345472);      // 50,331,648  q,k bf16 [32768,768]
  u16* vt  = (u16*)(ws + 76677120);      // 25,165,824  V^T bf16 [128][6][64][256]
  u16* yb  = (u16*)(ws + 101842944);     // 25,165,824  attn out bf16 [32768,384]
  if (ws_size < 127008768) return;

  cvt3<<<2048, 256, 0, stream>>>(x, xb, 3145728,
                                 w_attn, wab, 110592,
                                 w_proj, wpb, 36864);
  // GEMM1: BM=256 -> 128 M-tiles x 9 N-tiles = 1152 blocks, 512 thr, 3/CU
  gemm_qkv<<<1152, 512, 0, stream>>>(xb, wab, b_attn, qkv, vt);
  // attn: 768 blocks, 512 thr (8 waves, 2 q-tiles each)
  attn_k<<<768, 512, 0, stream>>>(qkv, vt, yb);
  // GEMM2: BM=128 -> 256 M-tiles x 3 N-tiles = 768 blocks, 512 thr, 4/CU
  gemm_proj<<<768, 512, 0, stream>>>(yb, wpb, b_proj, out);
}

// Round 19
// 104.809 us; speedup vs baseline: 3.5587x; 3.5587x over previous
//
#include <hip/hip_runtime.h>
#include <stdint.h>

// CausalSelfAttention: B=128 T=256 C=384 H=6 hd=64
// cvt(f32->bf16) -> GEMM1 qkv(+bias; q,k rows + V TRANSPOSED to vt) ->
// fused causal attention -> GEMM2 proj(+bias, f32)
// All matmuls via v_mfma_f32_16x16x32_bf16. Tolerance is bf16-floor (9.3e-2).

typedef unsigned short u16;
typedef __attribute__((ext_vector_type(8))) short short8;   // 8 bf16 (A/B frag)
typedef __attribute__((ext_vector_type(4))) short short4v;  // 4 bf16 (half frag)
typedef __attribute__((ext_vector_type(4))) float float4v;  // C/D frag

__device__ __forceinline__ u16 f2b(float f){            // f32 -> bf16 RNE
  union { float f; uint32_t u; } cv; cv.f = f;
  uint32_t u = cv.u;
  u += 0x7FFFu + ((u >> 16) & 1u);
  return (u16)(u >> 16);
}

__device__ __forceinline__ u16 f2b_t(float f){          // f32 -> bf16 truncate (1 op)
  union { float f; uint32_t u; } cv; cv.f = f;
  return (u16)(cv.u >> 16);
}

__device__ __forceinline__ float4v mfma16(short8 a, short8 b, float4v c){
  return __builtin_amdgcn_mfma_f32_16x16x32_bf16(a, b, c, 0, 0, 0);
}

// async global->LDS, 16B per lane. LDS dest = wave-uniform base + lane*16.
__device__ __forceinline__ void gld16(const void* g, void* l){
  __builtin_amdgcn_global_load_lds((__attribute__((address_space(1))) const void*)g,
                                   (__attribute__((address_space(3))) void*)l, 16, 0, 0);
}

// ---------------------------------------------------------------------------
// Kernel 1: f32 -> bf16 conversion for x, w_attn, w_proj
// ---------------------------------------------------------------------------
__global__ __launch_bounds__(256) void cvt3(
    const float* __restrict__ a, u16* __restrict__ da, int na,
    const float* __restrict__ b, u16* __restrict__ db, int nb,
    const float* __restrict__ c, u16* __restrict__ dc, int nc)
{
  const int total = na + nb + nc;  // counts in float4 units
  for (int i = blockIdx.x * blockDim.x + threadIdx.x; i < total;
       i += gridDim.x * blockDim.x){
    const float* s; u16* d; int j = i;
    if (j < na)           { s = a; d = da; }
    else if (j < na + nb) { j -= na; s = b; d = db; }
    else                  { j -= na + nb; s = c; d = dc; }
    const float4 v = ((const float4*)s)[j];
    ushort4 o;
    o.x = f2b(v.x); o.y = f2b(v.y); o.z = f2b(v.z); o.w = f2b(v.w);
    ((ushort4*)d)[j] = o;
  }
}

// ---------------------------------------------------------------------------
// Kernel 2: GEMM1 qkv = x(bf16) @ w_attn^T + bias. R16 schedule, TWO-buffer
// LDS (3rd buffer dead by schedule analysis): 48KB -> 3 blocks/CU by LDS =
// 6 waves/SIMD. launch_bounds (512,4): VGPR cap 128 (R18's (512,6) cap ~85
// SPILLED acc -> VGPR 40, 887MB scratch, 6x regression. Occupancy comes from
// LDS, not the cap -- G1 lesson).
//   tile t: vmcnt(3)->B1 ; frag ds_reads ; lgkm(0)->B2 ; STAGE(t+2,buf t&1) ; MFMA
// 512 thr / 8 waves, wave tile 64x64, acc[4][4], VGPR 64 (measured R16/R17).
// Epilogue: tn>=768 is V -> written TRANSPOSED to vt[b][h][d][t].
// Grid: 1-D XCD-chunked, yt-fastest.
// ---------------------------------------------------------------------------
__global__ __launch_bounds__(512, 4) void gemm_qkv(
    const u16* __restrict__ A, const u16* __restrict__ B,
    const float* __restrict__ bias, u16* __restrict__ QK,
    u16* __restrict__ Vt)
{
  constexpr int K    = 384;
  constexpr int NKT  = 12;
  constexpr int AB   = 256 * 32;               // 8192 u16 = 16KB per A buffer
  constexpr int BOFF = 2 * AB;
  __shared__ __align__(16) u16 SH[2 * AB + 2 * 4096];   // 48KB

  const int tid  = threadIdx.x;
  const int lane = tid & 63;
  const int wave = tid >> 6;
  const int lrow = lane & 15;
  const int g    = lane >> 4;

  // XCD-chunked decode, yt-fastest: 128 M-tiles (16/XCD) x 9 N-tiles
  const int id    = blockIdx.x;
  const int local = id >> 3;
  const int xtl   = local / 9;
  const int yt    = local - xtl * 9;
  const int tm    = ((id & 7) * 16 + xtl) << 8;
  const int tn    = yt << 7;
  const int wm    = (wave >> 1) * 64;          // 4 wave-rows
  const int wn    = (wave & 1) * 64;           // 2 wave-cols

  float4v acc[4][4];
  #pragma unroll
  for (int i = 0; i < 4; ++i)
    #pragma unroll
    for (int j = 0; j < 4; ++j) acc[i][j] = (float4v){0.f, 0.f, 0.f, 0.f};

  // staging: chunk c (1KB) = 16 rows x 32 cols; LDS granule q of row r holds
  // source granule q ^ ((r>>1)&3)  (R3/R6-verified conflict-free pattern)
  const int srow = lane >> 2;
  const int sg   = ((lane & 3) ^ ((lane >> 3) & 3)) << 3;
  const int key  = (lrow >> 1) & 3;

  auto STAGE = [&](int kt, int buf){           // 3 gld16 / thread
    #pragma unroll
    for (int j = 0; j < 2; ++j){               // A: 16 chunks, 2/wave
      const int c = wave * 2 + j;
      const int row = c * 16 + srow;
      gld16(A + (size_t)(tm + row) * K + kt * 32 + sg, &SH[buf * AB + c * 512]);
    }
    {                                          // B: 8 chunks, 1/wave
      const int c = wave;
      const int row = c * 16 + srow;
      gld16(B + (size_t)(tn + row) * K + kt * 32 + sg, &SH[BOFF + buf * 4096 + c * 512]);
    }
  };

  STAGE(0, 0);
  STAGE(1, 1);
  for (int kt = 0; kt < NKT; ++kt){
    const int b0 = kt & 1;
    if (kt + 1 < NKT) asm volatile("s_waitcnt vmcnt(3)" ::: "memory");
    else              asm volatile("s_waitcnt vmcnt(0)" ::: "memory");
    __builtin_amdgcn_s_barrier();

    const u16* Ac = &SH[b0 * AB];
    const u16* Bc = &SH[BOFF + b0 * 4096];
    short8 af[4], bf[4];
    #pragma unroll
    for (int i = 0; i < 4; ++i)
      af[i] = *(const short8*)&Ac[(wm + i * 16 + lrow) * 32 + ((g ^ key) << 3)];
    #pragma unroll
    for (int ni = 0; ni < 4; ++ni)
      bf[ni] = *(const short8*)&Bc[(wn + ni * 16 + lrow) * 32 + ((g ^ key) << 3)];

    asm volatile("s_waitcnt lgkmcnt(0)" ::: "memory");
    __builtin_amdgcn_sched_barrier(0);
    __builtin_amdgcn_s_barrier();              // B2: all frag reads complete

    if (kt + 2 < NKT) STAGE(kt + 2, b0);       // overwrite just-read buffer

    __builtin_amdgcn_s_setprio(1);
    #pragma unroll
    for (int ni = 0; ni < 4; ++ni)
      #pragma unroll
      for (int mi = 0; mi < 4; ++mi)
        acc[mi][ni] = mfma16(af[mi], bf[ni], acc[mi][ni]);
    __builtin_amdgcn_s_setprio(0);
  }

  // ---- epilogue. D layout: col=lane&15, row=(lane>>4)*4+reg (HW-verified).
  if (tn >= 768){
    // V third -> vt[b][h][d][t]; tm tile (256 rows) == one batch element
    const int bb = tm >> 8;
    #pragma unroll
    for (int ni = 0; ni < 4; ++ni){
      const int vcol0 = tn + wn - 768 + ni * 16;
      const int hh = vcol0 >> 6;
      const int dd = (vcol0 & 63) + lrow;
      const float bs = bias[tn + wn + ni * 16 + lrow];
      u16* vbase = Vt + ((size_t)(bb * 6 + hh) * 64 + dd) * 256;
      #pragma unroll
      for (int mi = 0; mi < 4; ++mi){
        #pragma unroll
        for (int r = 0; r < 4; ++r){
          const int t = wm + mi * 16 + g * 4 + r;
          vbase[t] = f2b(acc[mi][ni][r] + bs);
        }
      }
    }
  } else {
    #pragma unroll
    for (int mi = 0; mi < 4; ++mi){
      #pragma unroll
      for (int ni = 0; ni < 4; ++ni){
        const int gcol = tn + wn + ni * 16 + lrow;
        const float bs = bias[gcol];
        #pragma unroll
        for (int r = 0; r < 4; ++r){
          const int grow = tm + wm + mi * 16 + g * 4 + r;
          QK[(size_t)grow * 768 + gcol] = f2b(acc[mi][ni][r] + bs);
        }
      }
    }
  }
}

// ---------------------------------------------------------------------------
// Kernel 4: GEMM2  out = y @ w_proj^T + bias (f32 out). Two-buffer pipeline,
// BM=128, 8 waves (wave tile 32x64, acc[2][4]): LDS 32KB -> 4 blocks/CU by
// LDS = 8 waves/SIMD. launch_bounds (512,4): VGPR cap 128, no spill risk.
//   tile t: vmcnt(2)->B1 ; frag ds_reads ; lgkm(0)->B2 ; STAGE(t+2) ; MFMA
// ---------------------------------------------------------------------------
__global__ __launch_bounds__(512, 4) void gemm_proj(
    const u16* __restrict__ A, const u16* __restrict__ B,
    const float* __restrict__ bias, float* __restrict__ Cout)
{
  constexpr int K    = 384;
  constexpr int NKT  = 12;
  constexpr int AB   = 128 * 32;               // 4096 u16 = 8KB per A buffer
  constexpr int BOFF = 2 * AB;
  __shared__ __align__(16) u16 SH[2 * AB + 2 * 4096];   // 32KB

  const int tid  = threadIdx.x;
  const int lane = tid & 63;
  const int wave = tid >> 6;
  const int lrow = lane & 15;
  const int g    = lane >> 4;

  // XCD-chunked, yt-fastest: 256 M-tiles (32/XCD) x 3 N-tiles
  const int id    = blockIdx.x;
  const int local = id >> 3;
  const int xtl   = local / 3;
  const int yt    = local - xtl * 3;
  const int tm    = ((id & 7) * 32 + xtl) << 7;
  const int tn    = yt << 7;
  const int wm    = (wave >> 1) * 32;          // 4 wave-rows of 32
  const int wn    = (wave & 1) * 64;           // 2 wave-cols of 64

  float4v acc[2][4];
  #pragma unroll
  for (int i = 0; i < 2; ++i)
    #pragma unroll
    for (int j = 0; j < 4; ++j) acc[i][j] = (float4v){0.f, 0.f, 0.f, 0.f};

  const int srow = lane >> 2;
  const int sg   = ((lane & 3) ^ ((lane >> 3) & 3)) << 3;
  const int key  = (lrow >> 1) & 3;

  auto STAGE = [&](int kt, int buf){           // 2 gld16 / thread
    {                                          // A: 8 chunks, 1/wave
      const int row = wave * 16 + srow;
      gld16(A + (size_t)(tm + row) * K + kt * 32 + sg, &SH[buf * AB + wave * 512]);
    }
    {                                          // B: 8 chunks, 1/wave
      const int row = wave * 16 + srow;
      gld16(B + (size_t)(tn + row) * K + kt * 32 + sg, &SH[BOFF + buf * 4096 + wave * 512]);
    }
  };

  STAGE(0, 0);
  STAGE(1, 1);
  for (int kt = 0; kt < NKT; ++kt){
    const int b0 = kt & 1;
    if (kt + 1 < NKT) asm volatile("s_waitcnt vmcnt(2)" ::: "memory");
    else              asm volatile("s_waitcnt vmcnt(0)" ::: "memory");
    __builtin_amdgcn_s_barrier();

    const u16* Ac = &SH[b0 * AB];
    const u16* Bc = &SH[BOFF + b0 * 4096];
    short8 af[2], bf[4];
    #pragma unroll
    for (int i = 0; i < 2; ++i)
      af[i] = *(const short8*)&Ac[(wm + i * 16 + lrow) * 32 + ((g ^ key) << 3)];
    #pragma unroll
    for (int ni = 0; ni < 4; ++ni)
      bf[ni] = *(const short8*)&Bc[(wn + ni * 16 + lrow) * 32 + ((g ^ key) << 3)];

    asm volatile("s_waitcnt lgkmcnt(0)" ::: "memory");
    __builtin_amdgcn_sched_barrier(0);
    __builtin_amdgcn_s_barrier();

    if (kt + 2 < NKT) STAGE(kt + 2, b0);

    __builtin_amdgcn_s_setprio(1);
    #pragma unroll
    for (int ni = 0; ni < 4; ++ni)
      #pragma unroll
      for (int mi = 0; mi < 2; ++mi)
        acc[mi][ni] = mfma16(af[mi], bf[ni], acc[mi][ni]);
    __builtin_amdgcn_s_setprio(0);
  }

  #pragma unroll
  for (int mi = 0; mi < 2; ++mi)
    #pragma unroll
    for (int ni = 0; ni < 4; ++ni){
      const int gcol = tn + wn + ni * 16 + lrow;
      const float bs = bias[gcol];
      #pragma unroll
      for (int r = 0; r < 4; ++r){
        const int grow = tm + wm + mi * 16 + g * 4 + r;
        Cout[(size_t)grow * 384 + gcol] = acc[mi][ni][r] + bs;
      }
    }
}

// ---------------------------------------------------------------------------
// Kernel 3: fused causal attention (R17-measured), EIGHT waves (512 thr),
// one workgroup per (b,h), 64KB LDS -> 2 blocks/CU = 4 waves/SIMD.
// Each wave does 2 q-tiles {w, 15-w} = exactly 17 causal tiles (balanced).
// Swapped QK^T; softmax lane-local(+2 shfl); deferred normalization with
// shfl-transported rs; truncating P-convert; V^T pre-transposed from GEMM1.
// ---------------------------------------------------------------------------
__global__ __launch_bounds__(512, 4) void attn_k(
    const u16* __restrict__ qkv, const u16* __restrict__ vt,
    u16* __restrict__ y)
{
  __shared__ u16 Klds[256 * 64];   // K rows (128B), 16B granules XOR'd by row&7
  __shared__ u16 Vlds[64 * 256];   // V^T rows d (512B): unit u at u^(d&7)
  const int tid  = threadIdx.x;
  const int lane = tid & 63;
  const int wave = tid >> 6;       // 0..7
  const int lrow = lane & 15;
  const int g    = lane >> 4;
  const int bh = blockIdx.x;
  const int b = bh / 6, h = bh % 6;
  const u16* qb  = qkv + (size_t)b * 256 * 768 + h * 64;
  const u16* kb  = qb + 384;
  const u16* vtb = vt + (size_t)(b * 6 + h) * 64 * 256;

  // ---- stage K: 32 chunks, 4/wave
  #pragma unroll
  for (int j = 0; j < 4; ++j){
    const int c = wave * 4 + j;
    const int row = c * 8 + (lane >> 3);
    const int col = (((lane & 7) ^ (lane >> 3)) << 3);
    gld16(kb + (size_t)row * 768 + col, &Klds[c * 512]);
  }
  // ---- stage V^T: 32 chunks, 4/wave
  #pragma unroll
  for (int j = 0; j < 4; ++j){
    const int c  = wave * 4 + j;
    const int dd = c * 2 + (lane >> 5);
    const int q  = lane & 31;
    gld16(vtb + (size_t)dd * 256 + ((q ^ (dd & 7)) << 3), &Vlds[c * 512]);
  }
  __syncthreads();

  #pragma unroll
  for (int it = 0; it < 2; ++it){
    const int rb = (it == 0) ? wave : 15 - wave;   // pair = 17 tiles/wave
    const int q0 = rb * 16;
    const u16* qrow = qb + (size_t)(q0 + lrow) * 768 + g * 8;
    const short8 qf0 = *(const short8*)(qrow);
    const short8 qf1 = *(const short8*)(qrow + 32);

    float4v s[16];
    #pragma unroll
    for (int nt = 0; nt < 16; ++nt){
      if (nt <= rb){
        const int row = nt * 16 + lrow;
        const int swk = lrow & 7;
        const short8 k0 = *(const short8*)&Klds[row * 64 + ((g ^ swk) << 3)];
        const short8 k1 = *(const short8*)&Klds[row * 64 + (((4 + g) ^ swk) << 3)];
        float4v a = (float4v){0.f, 0.f, 0.f, 0.f};
        a = mfma16(k0, qf0, a);
        a = mfma16(k1, qf1, a);
        if (nt == rb){
          #pragma unroll
          for (int r = 0; r < 4; ++r)
            a[r] = (g * 4 + r > lrow) ? -1e30f : a[r];
        }
        s[nt] = a;
      }
    }

    float mx = -1e30f;
    #pragma unroll
    for (int nt = 0; nt < 16; ++nt) if (nt <= rb){
      #pragma unroll
      for (int r = 0; r < 4; ++r) mx = fmaxf(mx, s[nt][r]);
    }
    mx = fmaxf(mx, __shfl_xor(mx, 16));
    mx = fmaxf(mx, __shfl_xor(mx, 32));
    float sum = 0.f;
    #pragma unroll
    for (int nt = 0; nt < 16; ++nt) if (nt <= rb){
      #pragma unroll
      for (int r = 0; r < 4; ++r){
        const float p = exp2f((s[nt][r] - mx) * 0.18033688011112042f);
        s[nt][r] = p;
        sum += p;
      }
    }
    sum += __shfl_xor(sum, 16);
    sum += __shfl_xor(sum, 32);
    const float rs = 1.f / sum;            // rs for q = q0 + lrow
    float rsq[4];
    #pragma unroll
    for (int r = 0; r < 4; ++r) rsq[r] = __shfl(rs, g * 4 + r);

    float4v o0 = (float4v){0,0,0,0}, o1 = (float4v){0,0,0,0};
    float4v o2 = (float4v){0,0,0,0}, o3 = (float4v){0,0,0,0};
    const int swk = lrow & 7;
    #pragma unroll
    for (int kt = 0; kt < 8; ++kt){
      if (2 * kt <= rb){
        short8 pa;
        #pragma unroll
        for (int r = 0; r < 4; ++r) pa[r] = (short)f2b_t(s[2 * kt][r]);
        if (2 * kt + 1 <= rb){
          #pragma unroll
          for (int r = 0; r < 4; ++r) pa[4 + r] = (short)f2b_t(s[2 * kt + 1][r]);
        } else {
          #pragma unroll
          for (int r = 0; r < 4; ++r) pa[4 + r] = 0;
        }
        const int plo_e = (((kt * 4 +     (g >> 1)) ^ swk) << 3) + ((g & 1) << 2);
        const int phi_e = (((kt * 4 + 2 + (g >> 1)) ^ swk) << 3) + ((g & 1) << 2);
        #pragma unroll
        for (int dt = 0; dt < 4; ++dt){
          const u16* vrow = &Vlds[(size_t)(dt * 16 + lrow) * 256];
          const short4v vlo = *(const short4v*)&vrow[plo_e];
          const short4v vhi = *(const short4v*)&vrow[phi_e];
          const short8 bf = __builtin_shufflevector(vlo, vhi, 0,1,2,3,4,5,6,7);
          if      (dt == 0) o0 = mfma16(pa, bf, o0);
          else if (dt == 1) o1 = mfma16(pa, bf, o1);
          else if (dt == 2) o2 = mfma16(pa, bf, o2);
          else              o3 = mfma16(pa, bf, o3);
        }
      }
    }

    u16* yb = y + (size_t)(b * 256 + q0) * 384 + h * 64;
    #pragma unroll
    for (int r = 0; r < 4; ++r){
      const int q = g * 4 + r;
      yb[(size_t)q * 384 +  0 + lrow] = f2b(o0[r] * rsq[r]);
      yb[(size_t)q * 384 + 16 + lrow] = f2b(o1[r] * rsq[r]);
      yb[(size_t)q * 384 + 32 + lrow] = f2b(o2[r] * rsq[r]);
      yb[(size_t)q * 384 + 48 + lrow] = f2b(o3[r] * rsq[r]);
    }
  }
}

// ---------------------------------------------------------------------------
extern "C" void kernel_launch(void* const* d_in, const int* in_sizes, int n_in,
                              void* d_out, int out_size, void* d_ws, size_t ws_size,
                              hipStream_t stream)
{
  const float* x      = (const float*)d_in[0];
  const float* w_attn = (const float*)d_in[1];
  const float* b_attn = (const float*)d_in[2];
  const float* w_proj = (const float*)d_in[3];
  const float* b_proj = (const float*)d_in[4];
  float* out = (float*)d_out;

  // workspace layout (bytes)
  char* ws = (char*)d_ws;
  u16* xb  = (u16*)(ws);                 // 25,165,824  x bf16 [32768,384]
  u16* wab = (u16*)(ws + 25165824);      //    884,736  w_attn bf16 [1152,384]
  u16* wpb = (u16*)(ws + 26050560);      //    294,912  w_proj bf16 [384,384]
  u16* qkv = (u16*)(ws + 26345472);      // 50,331,648  q,k bf16 [32768,768]
  u16* vt  = (u16*)(ws + 76677120);      // 25,165,824  V^T bf16 [128][6][64][256]
  u16* yb  = (u16*)(ws + 101842944);     // 25,165,824  attn out bf16 [32768,384]
  if (ws_size < 127008768) return;

  cvt3<<<2048, 256, 0, stream>>>(x, xb, 3145728,
                                 w_attn, wab, 110592,
                                 w_proj, wpb, 36864);
  // GEMM1: BM=256 -> 128 M-tiles x 9 N-tiles = 1152 blocks, 512 thr, 3/CU
  gemm_qkv<<<1152, 512, 0, stream>>>(xb, wab, b_attn, qkv, vt);
  // attn: 768 blocks, 512 thr (8 waves, 2 q-tiles each)
  attn_k<<<768, 512, 0, stream>>>(qkv, vt, yb);
  // GEMM2: BM=128 -> 256 M-tiles x 3 N-tiles = 768 blocks, 512 thr, 4/CU
  gemm_proj<<<768, 512, 0, stream>>>(yb, wpb, b_proj, out);
}

// Round 20
// 104.670 us; speedup vs baseline: 3.5635x; 1.0013x over previous
//
#include <hip/hip_runtime.h>
#include <stdint.h>

// CausalSelfAttention: B=128 T=256 C=384 H=6 hd=64
// cvt(f32->bf16) -> GEMM1 qkv(+bias; q,k rows + V TRANSPOSED to vt) ->
// fused causal attention -> GEMM2 proj(+bias, f32)
// All matmuls via v_mfma_f32_16x16x32_bf16. Tolerance is bf16-floor (9.3e-2).
// R20 = R19 verbatim (best measured: 104.8us, absmax 0.03125).
// Journal of measured plateaus:
//  - gemm_qkv 48.5us @ MfmaUtil 22%: 5 schedules + 3 occupancy steps bracket
//    48-57us; K=384 (12 K-steps) denies the pipeline a steady state.
//  - cvt 12.4us: 77.6MB at HBM floor. Fusion into GEMM1 spilled (R15) or
//    trades equal fetch/LDS cost (f32 staging) -- net ~0.
//  - attn VGPR-bound at 4 waves/SIMD (s[16]=64 VGPR live P-state).
//  - proj all-resident, 8 waves/SIMD, zero tail.

typedef unsigned short u16;
typedef __attribute__((ext_vector_type(8))) short short8;   // 8 bf16 (A/B frag)
typedef __attribute__((ext_vector_type(4))) short short4v;  // 4 bf16 (half frag)
typedef __attribute__((ext_vector_type(4))) float float4v;  // C/D frag

__device__ __forceinline__ u16 f2b(float f){            // f32 -> bf16 RNE
  union { float f; uint32_t u; } cv; cv.f = f;
  uint32_t u = cv.u;
  u += 0x7FFFu + ((u >> 16) & 1u);
  return (u16)(u >> 16);
}

__device__ __forceinline__ u16 f2b_t(float f){          // f32 -> bf16 truncate (1 op)
  union { float f; uint32_t u; } cv; cv.f = f;
  return (u16)(cv.u >> 16);
}

__device__ __forceinline__ float4v mfma16(short8 a, short8 b, float4v c){
  return __builtin_amdgcn_mfma_f32_16x16x32_bf16(a, b, c, 0, 0, 0);
}

// async global->LDS, 16B per lane. LDS dest = wave-uniform base + lane*16.
__device__ __forceinline__ void gld16(const void* g, void* l){
  __builtin_amdgcn_global_load_lds((__attribute__((address_space(1))) const void*)g,
                                   (__attribute__((address_space(3))) void*)l, 16, 0, 0);
}

// ---------------------------------------------------------------------------
// Kernel 1: f32 -> bf16 conversion for x, w_attn, w_proj (HBM-floor bound)
// ---------------------------------------------------------------------------
__global__ __launch_bounds__(256) void cvt3(
    const float* __restrict__ a, u16* __restrict__ da, int na,
    const float* __restrict__ b, u16* __restrict__ db, int nb,
    const float* __restrict__ c, u16* __restrict__ dc, int nc)
{
  const int total = na + nb + nc;  // counts in float4 units
  for (int i = blockIdx.x * blockDim.x + threadIdx.x; i < total;
       i += gridDim.x * blockDim.x){
    const float* s; u16* d; int j = i;
    if (j < na)           { s = a; d = da; }
    else if (j < na + nb) { j -= na; s = b; d = db; }
    else                  { j -= na + nb; s = c; d = dc; }
    const float4 v = ((const float4*)s)[j];
    ushort4 o;
    o.x = f2b(v.x); o.y = f2b(v.y); o.z = f2b(v.z); o.w = f2b(v.w);
    ((ushort4*)d)[j] = o;
  }
}

// ---------------------------------------------------------------------------
// Kernel 2: GEMM1 qkv = x(bf16) @ w_attn^T + bias. Two-buffer counted-vmcnt
// 2-barrier pipeline: 48KB LDS -> 3 blocks/CU by LDS (6 waves/SIMD).
// launch_bounds (512,4): VGPR cap 128 -- (512,6)'s ~85 cap SPILLED acc in
// R18 (VGPR 40, 887MB scratch, 6x regression). Occupancy comes from LDS.
//   tile t: vmcnt(3)->B1 ; frag ds_reads ; lgkm(0)->B2 ; STAGE(t+2,buf t&1) ; MFMA
// 512 thr / 8 waves, wave tile 64x64, acc[4][4], VGPR 64 (measured).
// Epilogue: tn>=768 is V -> written TRANSPOSED to vt[b][h][d][t].
// Grid: 1-D XCD-chunked, yt-fastest (A-panel per XCD 3.1MB < 4MB L2).
// ---------------------------------------------------------------------------
__global__ __launch_bounds__(512, 4) void gemm_qkv(
    const u16* __restrict__ A, const u16* __restrict__ B,
    const float* __restrict__ bias, u16* __restrict__ QK,
    u16* __restrict__ Vt)
{
  constexpr int K    = 384;
  constexpr int NKT  = 12;
  constexpr int AB   = 256 * 32;               // 8192 u16 = 16KB per A buffer
  constexpr int BOFF = 2 * AB;
  __shared__ __align__(16) u16 SH[2 * AB + 2 * 4096];   // 48KB

  const int tid  = threadIdx.x;
  const int lane = tid & 63;
  const int wave = tid >> 6;
  const int lrow = lane & 15;
  const int g    = lane >> 4;

  // XCD-chunked decode, yt-fastest: 128 M-tiles (16/XCD) x 9 N-tiles
  const int id    = blockIdx.x;
  const int local = id >> 3;
  const int xtl   = local / 9;
  const int yt    = local - xtl * 9;
  const int tm    = ((id & 7) * 16 + xtl) << 8;
  const int tn    = yt << 7;
  const int wm    = (wave >> 1) * 64;          // 4 wave-rows
  const int wn    = (wave & 1) * 64;           // 2 wave-cols

  float4v acc[4][4];
  #pragma unroll
  for (int i = 0; i < 4; ++i)
    #pragma unroll
    for (int j = 0; j < 4; ++j) acc[i][j] = (float4v){0.f, 0.f, 0.f, 0.f};

  // staging: chunk c (1KB) = 16 rows x 32 cols; LDS granule q of row r holds
  // source granule q ^ ((r>>1)&3)  (R3/R6-verified conflict-free pattern)
  const int srow = lane >> 2;
  const int sg   = ((lane & 3) ^ ((lane >> 3) & 3)) << 3;
  const int key  = (lrow >> 1) & 3;

  auto STAGE = [&](int kt, int buf){           // 3 gld16 / thread
    #pragma unroll
    for (int j = 0; j < 2; ++j){               // A: 16 chunks, 2/wave
      const int c = wave * 2 + j;
      const int row = c * 16 + srow;
      gld16(A + (size_t)(tm + row) * K + kt * 32 + sg, &SH[buf * AB + c * 512]);
    }
    {                                          // B: 8 chunks, 1/wave
      const int c = wave;
      const int row = c * 16 + srow;
      gld16(B + (size_t)(tn + row) * K + kt * 32 + sg, &SH[BOFF + buf * 4096 + c * 512]);
    }
  };

  STAGE(0, 0);
  STAGE(1, 1);
  for (int kt = 0; kt < NKT; ++kt){
    const int b0 = kt & 1;
    if (kt + 1 < NKT) asm volatile("s_waitcnt vmcnt(3)" ::: "memory");
    else              asm volatile("s_waitcnt vmcnt(0)" ::: "memory");
    __builtin_amdgcn_s_barrier();

    const u16* Ac = &SH[b0 * AB];
    const u16* Bc = &SH[BOFF + b0 * 4096];
    short8 af[4], bf[4];
    #pragma unroll
    for (int i = 0; i < 4; ++i)
      af[i] = *(const short8*)&Ac[(wm + i * 16 + lrow) * 32 + ((g ^ key) << 3)];
    #pragma unroll
    for (int ni = 0; ni < 4; ++ni)
      bf[ni] = *(const short8*)&Bc[(wn + ni * 16 + lrow) * 32 + ((g ^ key) << 3)];

    asm volatile("s_waitcnt lgkmcnt(0)" ::: "memory");
    __builtin_amdgcn_sched_barrier(0);
    __builtin_amdgcn_s_barrier();              // B2: all frag reads complete

    if (kt + 2 < NKT) STAGE(kt + 2, b0);       // overwrite just-read buffer

    __builtin_amdgcn_s_setprio(1);
    #pragma unroll
    for (int ni = 0; ni < 4; ++ni)
      #pragma unroll
      for (int mi = 0; mi < 4; ++mi)
        acc[mi][ni] = mfma16(af[mi], bf[ni], acc[mi][ni]);
    __builtin_amdgcn_s_setprio(0);
  }

  // ---- epilogue. D layout: col=lane&15, row=(lane>>4)*4+reg (HW-verified).
  if (tn >= 768){
    // V third -> vt[b][h][d][t]; tm tile (256 rows) == one batch element
    const int bb = tm >> 8;
    #pragma unroll
    for (int ni = 0; ni < 4; ++ni){
      const int vcol0 = tn + wn - 768 + ni * 16;
      const int hh = vcol0 >> 6;
      const int dd = (vcol0 & 63) + lrow;
      const float bs = bias[tn + wn + ni * 16 + lrow];
      u16* vbase = Vt + ((size_t)(bb * 6 + hh) * 64 + dd) * 256;
      #pragma unroll
      for (int mi = 0; mi < 4; ++mi){
        #pragma unroll
        for (int r = 0; r < 4; ++r){
          const int t = wm + mi * 16 + g * 4 + r;
          vbase[t] = f2b(acc[mi][ni][r] + bs);
        }
      }
    }
  } else {
    #pragma unroll
    for (int mi = 0; mi < 4; ++mi){
      #pragma unroll
      for (int ni = 0; ni < 4; ++ni){
        const int gcol = tn + wn + ni * 16 + lrow;
        const float bs = bias[gcol];
        #pragma unroll
        for (int r = 0; r < 4; ++r){
          const int grow = tm + wm + mi * 16 + g * 4 + r;
          QK[(size_t)grow * 768 + gcol] = f2b(acc[mi][ni][r] + bs);
        }
      }
    }
  }
}

// ---------------------------------------------------------------------------
// Kernel 4: GEMM2  out = y @ w_proj^T + bias (f32 out). Two-buffer pipeline,
// BM=128, 8 waves (wave tile 32x64, acc[2][4]): LDS 32KB -> 4 blocks/CU by
// LDS = 8 waves/SIMD; 768 blocks all-resident (zero tail).
//   tile t: vmcnt(2)->B1 ; frag ds_reads ; lgkm(0)->B2 ; STAGE(t+2) ; MFMA
// ---------------------------------------------------------------------------
__global__ __launch_bounds__(512, 4) void gemm_proj(
    const u16* __restrict__ A, const u16* __restrict__ B,
    const float* __restrict__ bias, float* __restrict__ Cout)
{
  constexpr int K    = 384;
  constexpr int NKT  = 12;
  constexpr int AB   = 128 * 32;               // 4096 u16 = 8KB per A buffer
  constexpr int BOFF = 2 * AB;
  __shared__ __align__(16) u16 SH[2 * AB + 2 * 4096];   // 32KB

  const int tid  = threadIdx.x;
  const int lane = tid & 63;
  const int wave = tid >> 6;
  const int lrow = lane & 15;
  const int g    = lane >> 4;

  // XCD-chunked, yt-fastest: 256 M-tiles (32/XCD) x 3 N-tiles
  const int id    = blockIdx.x;
  const int local = id >> 3;
  const int xtl   = local / 3;
  const int yt    = local - xtl * 3;
  const int tm    = ((id & 7) * 32 + xtl) << 7;
  const int tn    = yt << 7;
  const int wm    = (wave >> 1) * 32;          // 4 wave-rows of 32
  const int wn    = (wave & 1) * 64;           // 2 wave-cols of 64

  float4v acc[2][4];
  #pragma unroll
  for (int i = 0; i < 2; ++i)
    #pragma unroll
    for (int j = 0; j < 4; ++j) acc[i][j] = (float4v){0.f, 0.f, 0.f, 0.f};

  const int srow = lane >> 2;
  const int sg   = ((lane & 3) ^ ((lane >> 3) & 3)) << 3;
  const int key  = (lrow >> 1) & 3;

  auto STAGE = [&](int kt, int buf){           // 2 gld16 / thread
    {                                          // A: 8 chunks, 1/wave
      const int row = wave * 16 + srow;
      gld16(A + (size_t)(tm + row) * K + kt * 32 + sg, &SH[buf * AB + wave * 512]);
    }
    {                                          // B: 8 chunks, 1/wave
      const int row = wave * 16 + srow;
      gld16(B + (size_t)(tn + row) * K + kt * 32 + sg, &SH[BOFF + buf * 4096 + wave * 512]);
    }
  };

  STAGE(0, 0);
  STAGE(1, 1);
  for (int kt = 0; kt < NKT; ++kt){
    const int b0 = kt & 1;
    if (kt + 1 < NKT) asm volatile("s_waitcnt vmcnt(2)" ::: "memory");
    else              asm volatile("s_waitcnt vmcnt(0)" ::: "memory");
    __builtin_amdgcn_s_barrier();

    const u16* Ac = &SH[b0 * AB];
    const u16* Bc = &SH[BOFF + b0 * 4096];
    short8 af[2], bf[4];
    #pragma unroll
    for (int i = 0; i < 2; ++i)
      af[i] = *(const short8*)&Ac[(wm + i * 16 + lrow) * 32 + ((g ^ key) << 3)];
    #pragma unroll
    for (int ni = 0; ni < 4; ++ni)
      bf[ni] = *(const short8*)&Bc[(wn + ni * 16 + lrow) * 32 + ((g ^ key) << 3)];

    asm volatile("s_waitcnt lgkmcnt(0)" ::: "memory");
    __builtin_amdgcn_sched_barrier(0);
    __builtin_amdgcn_s_barrier();

    if (kt + 2 < NKT) STAGE(kt + 2, b0);

    __builtin_amdgcn_s_setprio(1);
    #pragma unroll
    for (int ni = 0; ni < 4; ++ni)
      #pragma unroll
      for (int mi = 0; mi < 2; ++mi)
        acc[mi][ni] = mfma16(af[mi], bf[ni], acc[mi][ni]);
    __builtin_amdgcn_s_setprio(0);
  }

  #pragma unroll
  for (int mi = 0; mi < 2; ++mi)
    #pragma unroll
    for (int ni = 0; ni < 4; ++ni){
      const int gcol = tn + wn + ni * 16 + lrow;
      const float bs = bias[gcol];
      #pragma unroll
      for (int r = 0; r < 4; ++r){
        const int grow = tm + wm + mi * 16 + g * 4 + r;
        Cout[(size_t)grow * 384 + gcol] = acc[mi][ni][r] + bs;
      }
    }
}

// ---------------------------------------------------------------------------
// Kernel 3: fused causal attention, EIGHT waves (512 thr), one workgroup per
// (b,h), 64KB LDS; VGPR-bound at 4 waves/SIMD (s[16]=64 VGPR live P-state).
// Each wave does 2 q-tiles {w, 15-w} = exactly 17 causal tiles (balanced).
// Swapped QK^T; softmax lane-local(+2 shfl); deferred normalization with
// shfl-transported rs; truncating P-convert; V^T pre-transposed from GEMM1.
// ---------------------------------------------------------------------------
__global__ __launch_bounds__(512, 4) void attn_k(
    const u16* __restrict__ qkv, const u16* __restrict__ vt,
    u16* __restrict__ y)
{
  __shared__ u16 Klds[256 * 64];   // K rows (128B), 16B granules XOR'd by row&7
  __shared__ u16 Vlds[64 * 256];   // V^T rows d (512B): unit u at u^(d&7)
  const int tid  = threadIdx.x;
  const int lane = tid & 63;
  const int wave = tid >> 6;       // 0..7
  const int lrow = lane & 15;
  const int g    = lane >> 4;
  const int bh = blockIdx.x;
  const int b = bh / 6, h = bh % 6;
  const u16* qb  = qkv + (size_t)b * 256 * 768 + h * 64;
  const u16* kb  = qb + 384;
  const u16* vtb = vt + (size_t)(b * 6 + h) * 64 * 256;

  // ---- stage K: 32 chunks, 4/wave
  #pragma unroll
  for (int j = 0; j < 4; ++j){
    const int c = wave * 4 + j;
    const int row = c * 8 + (lane >> 3);
    const int col = (((lane & 7) ^ (lane >> 3)) << 3);
    gld16(kb + (size_t)row * 768 + col, &Klds[c * 512]);
  }
  // ---- stage V^T: 32 chunks, 4/wave
  #pragma unroll
  for (int j = 0; j < 4; ++j){
    const int c  = wave * 4 + j;
    const int dd = c * 2 + (lane >> 5);
    const int q  = lane & 31;
    gld16(vtb + (size_t)dd * 256 + ((q ^ (dd & 7)) << 3), &Vlds[c * 512]);
  }
  __syncthreads();

  #pragma unroll
  for (int it = 0; it < 2; ++it){
    const int rb = (it == 0) ? wave : 15 - wave;   // pair = 17 tiles/wave
    const int q0 = rb * 16;
    const u16* qrow = qb + (size_t)(q0 + lrow) * 768 + g * 8;
    const short8 qf0 = *(const short8*)(qrow);
    const short8 qf1 = *(const short8*)(qrow + 32);

    float4v s[16];
    #pragma unroll
    for (int nt = 0; nt < 16; ++nt){
      if (nt <= rb){
        const int row = nt * 16 + lrow;
        const int swk = lrow & 7;
        const short8 k0 = *(const short8*)&Klds[row * 64 + ((g ^ swk) << 3)];
        const short8 k1 = *(const short8*)&Klds[row * 64 + (((4 + g) ^ swk) << 3)];
        float4v a = (float4v){0.f, 0.f, 0.f, 0.f};
        a = mfma16(k0, qf0, a);
        a = mfma16(k1, qf1, a);
        if (nt == rb){
          #pragma unroll
          for (int r = 0; r < 4; ++r)
            a[r] = (g * 4 + r > lrow) ? -1e30f : a[r];
        }
        s[nt] = a;
      }
    }

    float mx = -1e30f;
    #pragma unroll
    for (int nt = 0; nt < 16; ++nt) if (nt <= rb){
      #pragma unroll
      for (int r = 0; r < 4; ++r) mx = fmaxf(mx, s[nt][r]);
    }
    mx = fmaxf(mx, __shfl_xor(mx, 16));
    mx = fmaxf(mx, __shfl_xor(mx, 32));
    float sum = 0.f;
    #pragma unroll
    for (int nt = 0; nt < 16; ++nt) if (nt <= rb){
      #pragma unroll
      for (int r = 0; r < 4; ++r){
        const float p = exp2f((s[nt][r] - mx) * 0.18033688011112042f);
        s[nt][r] = p;
        sum += p;
      }
    }
    sum += __shfl_xor(sum, 16);
    sum += __shfl_xor(sum, 32);
    const float rs = 1.f / sum;            // rs for q = q0 + lrow
    float rsq[4];
    #pragma unroll
    for (int r = 0; r < 4; ++r) rsq[r] = __shfl(rs, g * 4 + r);

    float4v o0 = (float4v){0,0,0,0}, o1 = (float4v){0,0,0,0};
    float4v o2 = (float4v){0,0,0,0}, o3 = (float4v){0,0,0,0};
    const int swk = lrow & 7;
    #pragma unroll
    for (int kt = 0; kt < 8; ++kt){
      if (2 * kt <= rb){
        short8 pa;
        #pragma unroll
        for (int r = 0; r < 4; ++r) pa[r] = (short)f2b_t(s[2 * kt][r]);
        if (2 * kt + 1 <= rb){
          #pragma unroll
          for (int r = 0; r < 4; ++r) pa[4 + r] = (short)f2b_t(s[2 * kt + 1][r]);
        } else {
          #pragma unroll
          for (int r = 0; r < 4; ++r) pa[4 + r] = 0;
        }
        const int plo_e = (((kt * 4 +     (g >> 1)) ^ swk) << 3) + ((g & 1) << 2);
        const int phi_e = (((kt * 4 + 2 + (g >> 1)) ^ swk) << 3) + ((g & 1) << 2);
        #pragma unroll
        for (int dt = 0; dt < 4; ++dt){
          const u16* vrow = &Vlds[(size_t)(dt * 16 + lrow) * 256];
          const short4v vlo = *(const short4v*)&vrow[plo_e];
          const short4v vhi = *(const short4v*)&vrow[phi_e];
          const short8 bf = __builtin_shufflevector(vlo, vhi, 0,1,2,3,4,5,6,7);
          if      (dt == 0) o0 = mfma16(pa, bf, o0);
          else if (dt == 1) o1 = mfma16(pa, bf, o1);
          else if (dt == 2) o2 = mfma16(pa, bf, o2);
          else              o3 = mfma16(pa, bf, o3);
        }
      }
    }

    u16* yb = y + (size_t)(b * 256 + q0) * 384 + h * 64;
    #pragma unroll
    for (int r = 0; r < 4; ++r){
      const int q = g * 4 + r;
      yb[(size_t)q * 384 +  0 + lrow] = f2b(o0[r] * rsq[r]);
      yb[(size_t)q * 384 + 16 + lrow] = f2b(o1[r] * rsq[r]);
      yb[(size_t)q * 384 + 32 + lrow] = f2b(o2[r] * rsq[r]);
      yb[(size_t)q * 384 + 48 + lrow] = f2b(o3[r] * rsq[r]);
    }
  }
}

// ---------------------------------------------------------------------------
extern "C" void kernel_launch(void* const* d_in, const int* in_sizes, int n_in,
                              void* d_out, int out_size, void* d_ws, size_t ws_size,
                              hipStream_t stream)
{
  const float* x      = (const float*)d_in[0];
  const float* w_attn = (const float*)d_in[1];
  const float* b_attn = (const float*)d_in[2];
  const float* w_proj = (const float*)d_in[3];
  const float* b_proj = (const float*)d_in[4];
  float* out = (float*)d_out;

  // workspace layout (bytes)
  char* ws = (char*)d_ws;
  u16* xb  = (u16*)(ws);                 // 25,165,824  x bf16 [32768,384]
  u16* wab = (u16*)(ws + 25165824);      //    884,736  w_attn bf16 [1152,384]
  u16* wpb = (u16*)(ws + 26050560);      //    294,912  w_proj bf16 [384,384]
  u16* qkv = (u16*)(ws + 26345472);      // 50,331,648  q,k bf16 [32768,768]
  u16* vt  = (u16*)(ws + 76677120);      // 25,165,824  V^T bf16 [128][6][64][256]
  u16* yb  = (u16*)(ws + 101842944);     // 25,165,824  attn out bf16 [32768,384]
  if (ws_size < 127008768) return;

  cvt3<<<2048, 256, 0, stream>>>(x, xb, 3145728,
                                 w_attn, wab, 110592,
                                 w_proj, wpb, 36864);
  // GEMM1: BM=256 -> 128 M-tiles x 9 N-tiles = 1152 blocks, 512 thr, 3/CU
  gemm_qkv<<<1152, 512, 0, stream>>>(xb, wab, b_attn, qkv, vt);
  // attn: 768 blocks, 512 thr (8 waves, 2 q-tiles each)
  attn_k<<<768, 512, 0, stream>>>(qkv, vt, yb);
  // GEMM2: BM=128 -> 256 M-tiles x 3 N-tiles = 768 blocks, 512 thr, 4/CU
  gemm_proj<<<768, 512, 0, stream>>>(yb, wpb, b_proj, out);
}